// Round 2
// baseline (1817.999 us; speedup 1.0000x reference)
//
#include <hip/hip_runtime.h>

// Correlation: B=4 C=256 H=64 W=96, 21x21 displacements, stride2=2.
// out[b, dyp*21+k, y, x] = (1/256) * sum_c in1[b,c,y,x] * in2[b,c,y+2(dyp-10), x+2(k-10)]
//
// Block = (b, dyp, ytile of 8 rows). 192 threads = 24 x-groups x 8 rows.
// Each thread computes 4 x-positions (x, x+2, x+4, x+6) x 21 displacements = 84 acc,
// fed by 24 LDS b-words + 4 a-words per channel (3.5 FMA per LDS word).

#define CC 256
#define HH 64
#define WW 96
#define ND 21
#define TY 8
#define KC 4
#define LWB 136      // in2 staged row: cols -20..115
#define SB  138      // padded LDS stride for in2 rows (bank spread)
#define SA  98       // padded LDS stride for in1 rows

__global__ __launch_bounds__(192)
void Correlation_68367289417895_kernel(const float* __restrict__ in1,
                                       const float* __restrict__ in2,
                                       float* __restrict__ out) {
    const int bid   = blockIdx.x;           // (b*21 + dyp)*8 + ytile
    const int ytile = bid & 7;
    const int dyp   = (bid >> 3) % ND;
    const int b     = bid / (ND * 8);
    const int y0    = ytile * TY;
    const int dy2   = 2 * (dyp - 10);       // y2 = y + dy2

    const int tid   = threadIdx.x;
    const int g     = tid % 24;
    const int r     = tid / 24;             // 0..7
    const int xbase = (g < 12) ? (8 * g) : (8 * (g - 12) + 1);
    const int y     = y0 + r;

    __shared__ float ldsB[KC * TY * SB];
    __shared__ float ldsA[KC * TY * SA];

    float acc[4][ND];
#pragma unroll
    for (int j = 0; j < 4; ++j)
#pragma unroll
        for (int k = 0; k < ND; ++k) acc[j][k] = 0.0f;

    const size_t HW = (size_t)HH * WW;
    const float* p1base = in1 + (size_t)b * CC * HW;
    const float* p2base = in2 + (size_t)b * CC * HW;

    for (int c0 = 0; c0 < CC; c0 += KC) {
        __syncthreads();
        // stage in1: KC*TY*96 = 3072 words, 16 per thread, coalesced
#pragma unroll
        for (int i = tid; i < KC * TY * WW; i += 192) {
            const int c   = i / (TY * WW);
            const int rem = i - c * (TY * WW);
            const int rr  = rem / WW;
            const int col = rem - rr * WW;
            ldsA[(c * TY + rr) * SA + col] =
                p1base[(size_t)(c0 + c) * HW + (y0 + rr) * WW + col];
        }
        // stage in2 (zero-padded): KC*TY*136 = 4352 words
#pragma unroll
        for (int i = tid; i < KC * TY * LWB; i += 192) {
            const int c    = i / (TY * LWB);
            const int rem  = i - c * (TY * LWB);
            const int rr   = rem / LWB;
            const int lcol = rem - rr * LWB;
            const int col  = lcol - 20;
            const int y2   = y0 + rr + dy2;
            float v = 0.0f;
            if (col >= 0 && col < WW && y2 >= 0 && y2 < HH)
                v = p2base[(size_t)(c0 + c) * HW + y2 * WW + col];
            ldsB[(c * TY + rr) * SB + lcol] = v;
        }
        __syncthreads();

#pragma unroll
        for (int cc = 0; cc < KC; ++cc) {
            const float* bp = &ldsB[(cc * TY + r) * SB + xbase];
            const float* ap = &ldsA[(cc * TY + r) * SA + xbase];
            float bv[24];
#pragma unroll
            for (int t = 0; t < 24; ++t) bv[t] = bp[2 * t];
            float av[4];
#pragma unroll
            for (int j = 0; j < 4; ++j) av[j] = ap[2 * j];
#pragma unroll
            for (int j = 0; j < 4; ++j)
#pragma unroll
                for (int k = 0; k < ND; ++k)
                    acc[j][k] += av[j] * bv[j + k];
        }
    }

    const float scale = 1.0f / (float)CC;
    float* po = out + (((size_t)b * (ND * ND) + (size_t)dyp * ND) * HH + y) * WW + xbase;
#pragma unroll
    for (int k = 0; k < ND; ++k)
#pragma unroll
        for (int j = 0; j < 4; ++j)
            po[(size_t)k * HW + 2 * j] = acc[j][k] * scale;
}

extern "C" void kernel_launch(void* const* d_in, const int* in_sizes, int n_in,
                              void* d_out, int out_size, void* d_ws, size_t ws_size,
                              hipStream_t stream) {
    const float* in1 = (const float*)d_in[0];
    const float* in2 = (const float*)d_in[1];
    float* out = (float*)d_out;

    const int nblocks = 4 * ND * (HH / TY);  // 4*21*8 = 672
    Correlation_68367289417895_kernel<<<dim3(nblocks), dim3(192), 0, stream>>>(in1, in2, out);
}

// Round 3
// 426.891 us; speedup vs baseline: 4.2587x; 4.2587x over previous
//
#include <hip/hip_runtime.h>

// Correlation: B=4 C=256 H=64 W=96, 21x21 displacements, stride2=2.
// out[b, dyp*21+k, y, x] = (1/256) * sum_c in1[b,c,y,x] * in2[b,c,y+2(dyp-10), x+2(k-10)]
//
// Register tile: each thread computes 4 x-positions (x, x+2, x+4, x+6) x 21 disps.
// KEY FIX vs R2: LDS rows are stored de-interleaved by column parity, so each
// thread's 24-word b-window is CONTIGUOUS -> 6 aligned ds_read_b128, lanes at
// 16B stride (conflict-free), instead of 24 stride-8 ds_read_b32 (3-way conflicts).

#define CC 256
#define HH 64
#define WW 96
#define ND 21
#define TY 8
#define KC 4
#define BROW 72            // padded parity-row stride for in2 (68 valid entries)
#define AROW 52            // padded parity-row stride for in1 (48 valid entries)
#define HW (HH * WW)

__global__ __launch_bounds__(192)
void Correlation_68367289417895_kernel(const float* __restrict__ in1,
                                       const float* __restrict__ in2,
                                       float* __restrict__ out) {
    const int bid   = blockIdx.x;            // (b*21 + dyp)*8 + ytile
    const int ytile = bid & 7;
    const int dyp   = (bid >> 3) % ND;
    const int b     = bid / (ND * 8);
    const int y0    = ytile * TY;
    const int dy2   = 2 * (dyp - 10);

    const int tid = threadIdx.x;
    const int g   = tid % 24;
    const int r   = tid / 24;                // 0..7
    const int p   = (g < 12) ? 0 : 1;        // column parity of this thread's bases
    const int gg  = (g < 12) ? g : g - 12;   // 0..11
    const int xb  = 8 * gg + p;              // base x; covers xb, xb+2, xb+4, xb+6
    const int i0  = 4 * gg;                  // base index in parity array
    const int y   = y0 + r;

    // parity-split LDS: [parity][channel][row][idx]
    __shared__ __align__(16) float Bsh[2 * KC * TY * BROW];  // in2, cols -20..115
    __shared__ __align__(16) float Ash[2 * KC * TY * AROW];  // in1, cols 0..95

    float acc[4][ND];
#pragma unroll
    for (int j = 0; j < 4; ++j)
#pragma unroll
        for (int k = 0; k < ND; ++k) acc[j][k] = 0.0f;

    const float* p1 = in1 + (size_t)b * CC * HW;
    const float* p2 = in2 + (size_t)b * CC * HW;

    for (int c0 = 0; c0 < CC; c0 += KC) {
        __syncthreads();
        // ---- stage in1: KC*TY rows x 96 cols = 768 float4, de-interleave ----
#pragma unroll
        for (int t = 0; t < 4; ++t) {
            const int q   = tid + 192 * t;           // 0..767
            const int c   = q / (TY * 24);           // 24 float4 per row
            const int rem = q - c * (TY * 24);
            const int rr  = rem / 24;
            const int i   = rem - rr * 24;
            const float4 v = *(const float4*)(p1 + (size_t)(c0 + c) * HW + (y0 + rr) * WW + 4 * i);
            const int base = (c * TY + rr) * AROW + 2 * i;
            *(float2*)&Ash[base]                  = make_float2(v.x, v.z);  // even cols
            *(float2*)&Ash[KC * TY * AROW + base] = make_float2(v.y, v.w);  // odd cols
        }
        // ---- stage in2: KC*TY rows x cols -20..115 = 34 float4/row, zero-padded ----
#pragma unroll
        for (int t = 0; t < 6; ++t) {
            const int q = tid + 192 * t;             // 0..1087
            if (q < KC * TY * 34) {
                const int c   = q / (TY * 34);
                const int rem = q - c * (TY * 34);
                const int rr  = rem / 34;
                const int i   = rem - rr * 34;       // float4 covers cols -20+4i .. -20+4i+3
                const int y2  = y0 + rr + dy2;
                float4 v = make_float4(0.f, 0.f, 0.f, 0.f);
                if (y2 >= 0 && y2 < HH && i >= 5 && i <= 28)
                    v = *(const float4*)(p2 + (size_t)(c0 + c) * HW + y2 * WW + (4 * i - 20));
                const int base = (c * TY + rr) * BROW + 2 * i;
                *(float2*)&Bsh[base]                  = make_float2(v.x, v.z);
                *(float2*)&Bsh[KC * TY * BROW + base] = make_float2(v.y, v.w);
            }
        }
        __syncthreads();

        // ---- compute: per channel, 6+1 aligned b128 LDS reads feed 84 FMAs ----
#pragma unroll
        for (int cc = 0; cc < KC; ++cc) {
            const float* Bp = &Bsh[((p * KC + cc) * TY + r) * BROW + i0];
            const float* Ap = &Ash[((p * KC + cc) * TY + r) * AROW + i0];
            float bv[24];
#pragma unroll
            for (int t = 0; t < 6; ++t) {
                const float4 v = *(const float4*)(Bp + 4 * t);
                bv[4 * t + 0] = v.x; bv[4 * t + 1] = v.y;
                bv[4 * t + 2] = v.z; bv[4 * t + 3] = v.w;
            }
            const float4 a4 = *(const float4*)Ap;
            const float av[4] = {a4.x, a4.y, a4.z, a4.w};
#pragma unroll
            for (int j = 0; j < 4; ++j)
#pragma unroll
                for (int k = 0; k < ND; ++k)
                    acc[j][k] += av[j] * bv[j + k];
        }
    }

    const float scale = 1.0f / (float)CC;
    float* po = out + (((size_t)b * (ND * ND) + (size_t)dyp * ND) * HH + y) * WW + xb;
#pragma unroll
    for (int k = 0; k < ND; ++k)
#pragma unroll
        for (int j = 0; j < 4; ++j)
            po[(size_t)k * HW + 2 * j] = acc[j][k] * scale;
}

extern "C" void kernel_launch(void* const* d_in, const int* in_sizes, int n_in,
                              void* d_out, int out_size, void* d_ws, size_t ws_size,
                              hipStream_t stream) {
    const float* in1 = (const float*)d_in[0];
    const float* in2 = (const float*)d_in[1];
    float* out = (float*)d_out;

    const int nblocks = 4 * ND * (HH / TY);  // 672
    Correlation_68367289417895_kernel<<<dim3(nblocks), dim3(192), 0, stream>>>(in1, in2, out);
}

// Round 4
// 195.382 us; speedup vs baseline: 9.3048x; 2.1849x over previous
//
#include <hip/hip_runtime.h>

// Correlation as banded Gram via bf16 MFMA.
// out[b, dyp*21+k, y, x] = (1/256) * sum_c in1[b,c,y,x] * in2[b,c,y+2(dyp-10), x+2(k-10)]
// Parity split: x = 2*xe+par  ->  G[xe, ue=xe+k] = sum_c A[c,xe]*B[c,ue-10], band k in [0,21).
// Tiles (Xi,Uj) of 16x16, K=256 via 8x mfma_f32_16x16x32_bf16.

typedef short bf16x8 __attribute__((ext_vector_type(8)));
typedef float f32x4  __attribute__((ext_vector_type(4)));

#define HW     6144      // 64*96
#define PLANE  24576     // shorts per (b,y) transposed plane: 2*48*256
#define BP     264       // padded B row stride (shorts), 264=33*8, stride mod 32 words = 4
#define BSLOT  25344     // 96 rows * 264 shorts
#define ABASE  0         // A: unpadded [96][256] shorts = 24576
#define B0BASE 24576
#define B1BASE 49920     // 24576+25344
#define SMEMSH 75264     // total shorts = 150528 B
#define SCR    2037      // scratch floats per slot: 21*97

__device__ __forceinline__ short f2bf(float f) {
    union { float f; unsigned u; } x; x.f = f;
    unsigned u = x.u;
    unsigned r = (u + 0x7fffu + ((u >> 16) & 1u)) >> 16;
    return (short)r;
}

// ---------------- pre-pass: fp32 [b][c][y][x] -> bf16 [b][y][par][col][c] ----------------
__global__ __launch_bounds__(256)
void corr_prepass(const float* __restrict__ in1, const float* __restrict__ in2,
                  short* __restrict__ dstA, short* __restrict__ dstB) {
    const int bid = blockIdx.x;
    const int sel = bid >> 8;
    const int by  = bid & 255;
    const int b = by >> 6, y = by & 63;
    const float* src = sel ? in2 : in1;
    short* dst = sel ? dstB : dstA;

    __shared__ __align__(16) short T[96 * 266];   // [x][c], stride 266
    const int t = threadIdx.x;
    const int cg = t / 24, i = t % 24;            // i: float4 index along x

    if (cg < 10) {
#pragma unroll 4
        for (int it = 0; it < 26; ++it) {
            const int ci = it * 10 + cg;
            if (ci < 256) {
                const float4 v = *(const float4*)(src + ((size_t)(b * 256 + ci) * 64 + y) * 96 + 4 * i);
                T[(4 * i + 0) * 266 + ci] = f2bf(v.x);
                T[(4 * i + 1) * 266 + ci] = f2bf(v.y);
                T[(4 * i + 2) * 266 + ci] = f2bf(v.z);
                T[(4 * i + 3) * 266 + ci] = f2bf(v.w);
            }
        }
    }
    __syncthreads();

    unsigned* gout = (unsigned*)(dst + (size_t)by * PLANE);
#pragma unroll 4
    for (int it = 0; it < 48; ++it) {
        const int d  = it * 256 + t;      // dword index, [0,12288)
        const int R  = d >> 7;            // par*48+col
        const int cd = d & 127;
        const int x  = (R < 48) ? (2 * R) : (2 * (R - 48) + 1);
        gout[d] = *(const unsigned*)&T[x * 266 + 2 * cd];
    }
}

// ---------------- main kernel ----------------
__global__ __launch_bounds__(256, 1)
void corr_mfma(const short* __restrict__ Ag, const short* __restrict__ Bg,
               float* __restrict__ out) {
    const int by = blockIdx.x;            // b*64+y
    const int b = by >> 6, y = by & 63;
    const int tid  = threadIdx.x;
    const int w    = tid >> 6, lane = tid & 63;
    const int par  = w & 1,  slot = w >> 1;
    const int n    = lane & 15, q = lane >> 4;

    __shared__ __align__(16) short smem[SMEMSH];
    float* scr = (float*)smem;            // scratch aliases dead A region after preload

    // stage A (contiguous copy) + B pair 0
    {
        const short* src = Ag + (size_t)by * PLANE;
#pragma unroll
        for (int it = 0; it < 12; ++it) {
            const int j = it * 256 + tid;
            *(bf16x8*)&smem[ABASE + j * 8] = *(const bf16x8*)(src + j * 8);
        }
    }
#pragma unroll
    for (int s = 0; s < 2; ++s) {
        int y2 = y + 2 * s - 20;
        y2 = min(max(y2, 0), 63);
        const short* src = Bg + ((size_t)(b * 64 + y2)) * PLANE;
        short* dstp = &smem[s ? B1BASE : B0BASE];
#pragma unroll
        for (int it = 0; it < 12; ++it) {
            const int j = it * 256 + tid;
            *(bf16x8*)&dstp[(j >> 5) * BP + (j & 31) * 8] = *(const bf16x8*)(src + j * 8);
        }
    }
    __syncthreads();

    // preload A fragments: af[Xi][ks], m=lane&15, k-chunk q
    bf16x8 af[3][8];
#pragma unroll
    for (int Xi = 0; Xi < 3; ++Xi)
#pragma unroll
        for (int ks = 0; ks < 8; ++ks)
            af[Xi][ks] = *(const bf16x8*)&smem[ABASE + (par * 48 + Xi * 16 + n) * 256 + ks * 32 + q * 8];
    __syncthreads();   // protect scratch (A region) from early writers

    const int  r0  = n - 10;  const bool v0 = (n >= 10);
    const int  r3  = n + 38;  const bool v3 = (n < 10);
    const int  r0c = v0 ? r0 : 0;
    const int  r3c = v3 ? r3 : 0;

    for (int p = 0; p <= 10; ++p) {
        const int dyp = 2 * p + slot;
        const int y2  = y + 2 * dyp - 20;
        const bool live = (dyp < 21) && (y2 >= 0) && (y2 < 64);

        f32x4 acc[9];
#pragma unroll
        for (int t2 = 0; t2 < 9; ++t2) acc[t2] = (f32x4)0.0f;

        if (live) {
            const short* Bp = &smem[(slot ? B1BASE : B0BASE) + par * 48 * BP];
#pragma unroll
            for (int ks = 0; ks < 8; ++ks) {
                const int ko = ks * 32 + q * 8;
                bf16x8 b0 = *(const bf16x8*)&Bp[r0c * BP + ko];      if (!v0) b0 = 0;
                bf16x8 b1 = *(const bf16x8*)&Bp[(n + 6)  * BP + ko];
                bf16x8 b2 = *(const bf16x8*)&Bp[(n + 22) * BP + ko];
                bf16x8 b3 = *(const bf16x8*)&Bp[r3c * BP + ko];      if (!v3) b3 = 0;
                acc[0] = __builtin_amdgcn_mfma_f32_16x16x32_bf16(af[0][ks], b0, acc[0], 0, 0, 0);
                acc[1] = __builtin_amdgcn_mfma_f32_16x16x32_bf16(af[0][ks], b1, acc[1], 0, 0, 0);
                acc[2] = __builtin_amdgcn_mfma_f32_16x16x32_bf16(af[0][ks], b2, acc[2], 0, 0, 0);
                acc[3] = __builtin_amdgcn_mfma_f32_16x16x32_bf16(af[1][ks], b1, acc[3], 0, 0, 0);
                acc[4] = __builtin_amdgcn_mfma_f32_16x16x32_bf16(af[1][ks], b2, acc[4], 0, 0, 0);
                acc[5] = __builtin_amdgcn_mfma_f32_16x16x32_bf16(af[1][ks], b3, acc[5], 0, 0, 0);
                acc[6] = __builtin_amdgcn_mfma_f32_16x16x32_bf16(af[2][ks], b2, acc[6], 0, 0, 0);
                acc[7] = __builtin_amdgcn_mfma_f32_16x16x32_bf16(af[2][ks], b3, acc[7], 0, 0, 0);
                // acc[8] = (X2,U4): B columns all OOB -> structurally zero
            }
        }

        // write C tiles into scratch [slot][21][97] at (k, x=2*xe+par)
        if (dyp < 21) {
            float* sc = scr + slot * SCR;
            const int mb = q * 4;
#pragma unroll
            for (int t2 = 0; t2 < 9; ++t2) {
                const int Xi = (t2 < 3) ? 0 : (t2 < 6 ? 1 : 2);
                static const int UJ[9] = {0, 1, 2, 1, 2, 3, 2, 3, 4};
                const int ub = UJ[t2] * 16;
#pragma unroll
                for (int r = 0; r < 4; ++r) {
                    const int xe = Xi * 16 + mb + r;
                    const int k  = ub + n - xe;
                    if ((unsigned)k < 21u)
                        sc[k * 97 + 2 * xe + par] = acc[t2][r];
                }
            }
        }
        __syncthreads();

        // cooperative coalesced store of both dyps + stage next pair
#pragma unroll
        for (int it = 0; it < 16; ++it) {
            const int e = it * 256 + tid;          // [0,4096); valid < 4032
            if (e < 4032) {
                const int s  = e / 2016;
                const int f  = e - s * 2016;
                const int k  = f / 96;
                const int x  = f - k * 96;
                const int dd = 2 * p + s;
                if (dd < 21)
                    out[((size_t)(b * 441 + dd * 21 + k) * 64 + y) * 96 + x] =
                        scr[s * SCR + k * 97 + x] * (1.0f / 256.0f);
            }
        }
        if (p < 10) {
#pragma unroll
            for (int s = 0; s < 2; ++s) {
                int y2n = y + 2 * (2 * (p + 1) + s) - 20;
                y2n = min(max(y2n, 0), 63);
                const short* src = Bg + ((size_t)(b * 64 + y2n)) * PLANE;
                short* dstp = &smem[s ? B1BASE : B0BASE];
#pragma unroll
                for (int it = 0; it < 12; ++it) {
                    const int j = it * 256 + tid;
                    *(bf16x8*)&dstp[(j >> 5) * BP + (j & 31) * 8] = *(const bf16x8*)(src + j * 8);
                }
            }
        }
        __syncthreads();
    }
}

extern "C" void kernel_launch(void* const* d_in, const int* in_sizes, int n_in,
                              void* d_out, int out_size, void* d_ws, size_t ws_size,
                              hipStream_t stream) {
    const float* in1 = (const float*)d_in[0];
    const float* in2 = (const float*)d_in[1];
    float* out = (float*)d_out;

    short* Ag = (short*)d_ws;                       // 4*64*PLANE shorts = 12.58 MB
    short* Bg = Ag + (size_t)4 * 64 * PLANE;        // another 12.58 MB

    corr_prepass<<<dim3(512), dim3(256), 0, stream>>>(in1, in2, Ag, Bg);
    corr_mfma<<<dim3(256), dim3(256), 0, stream>>>(Ag, Bg, out);
}

// Round 5
// 150.062 us; speedup vs baseline: 12.1150x; 1.3020x over previous
//
#include <hip/hip_runtime.h>

// Correlation via bf16 MFMA banded Gram.
// out[b, dyp*21+k, y, x] = (1/256) * sum_c in1[b,c,y,x] * in2[b,c,y+2(dyp-10), x+2(k-10)]
// Layouts (workspace): Ag/Bg[b*64+y][par*48+col][c] bf16, x = 2*col+par.
//
// R5 structure: prepass = tiled transpose (3KB-contiguous reads, b128 LDS ops).
// main: block=(b,y2,pgroup); B(b,y2) in LDS once; A-frags gathered from global
// (L3-resident) per dyp; 66KB LDS -> 2 blocks/CU, 512 blocks -> 8 waves/CU.

typedef short bf16x8 __attribute__((ext_vector_type(8)));
typedef float f32x4  __attribute__((ext_vector_type(4)));

#define PLANE 24576         // shorts per (b,y) plane: 96 rows * 256 c
#define BP    260           // padded B LDS row stride (shorts): 130 words == 2 mod 32
#define ST    40            // prepass LDS row stride (shorts)

__device__ __forceinline__ short f2bf(float f) {
    union { float f; unsigned u; } x; x.f = f;
    const unsigned u = x.u;
    return (short)((u + 0x7fffu + ((u >> 16) & 1u)) >> 16);
}

// ---------- prepass: fp32 [b][c][y][x] -> bf16 [b*64+y][par*48+col][c] ----------
// block = (sel, b, ytile of 8, ctile of 32ch). Reads 3KB contiguous per channel.
__global__ __launch_bounds__(256)
void corr_prepass(const float* __restrict__ in1, const float* __restrict__ in2,
                  short* __restrict__ dstA, short* __restrict__ dstB) {
    const int bid = blockIdx.x;
    const int sel = bid >> 8;
    const int r   = bid & 255;
    const int b   = r >> 6;
    const int yt  = (r >> 3) & 7;
    const int ct  = r & 7;
    const int c0 = ct * 32, y0 = yt * 8;
    const float* src = sel ? in2 : in1;
    short* dst = sel ? dstB : dstA;

    __shared__ __align__(16) short T[768 * ST];   // [xx = yy*96+x][32c], 61.4 KB
    const int tid = threadIdx.x;

#pragma unroll
    for (int it = 0; it < 3; ++it) {
        const int d = it * 256 + tid;            // [0,768)
        const int g = d / 192;                   // channel octet 0..3
        const int f = d - g * 192;               // float4 index in 8y*96x chunk
        float4 v[8];
#pragma unroll
        for (int j = 0; j < 8; ++j) {
            const int c = c0 + g * 8 + j;
            v[j] = *(const float4*)(src + ((size_t)(b * 256 + c) * 64 + y0) * 96 + 4 * f);
        }
        bf16x8 w0, w1, w2, w3;
#pragma unroll
        for (int j = 0; j < 8; ++j) {
            w0[j] = f2bf(v[j].x); w1[j] = f2bf(v[j].y);
            w2[j] = f2bf(v[j].z); w3[j] = f2bf(v[j].w);
        }
        const int perm = ((g ^ (f & 3)) * 8);
        const int base = 4 * f * ST + perm;
        *(bf16x8*)&T[base]          = w0;
        *(bf16x8*)&T[base + ST]     = w1;
        *(bf16x8*)&T[base + 2*ST]   = w2;
        *(bf16x8*)&T[base + 3*ST]   = w3;
    }
    __syncthreads();

#pragma unroll
    for (int it = 0; it < 12; ++it) {
        const int D  = it * 256 + tid;           // [0,3072)
        const int Rl = D >> 2, gp = D & 3;
        const int yy  = Rl / 96;
        const int rl  = Rl - yy * 96;
        const int par = rl / 48;
        const int col = rl - par * 48;
        const int x   = 2 * col + par;
        const int xx  = yy * 96 + x;
        const int perm = ((gp ^ ((xx >> 2) & 3)) * 8);
        const bf16x8 w = *(const bf16x8*)&T[xx * ST + perm];
        const size_t Rg = (size_t)(b * 64 + y0 + yy) * 96 + par * 48 + col;
        *(bf16x8*)(dst + Rg * 256 + c0 + gp * 8) = w;
    }
}

// ---------- main kernel ----------
__global__ __launch_bounds__(256, 2)
void corr_mfma(const short* __restrict__ Ag, const short* __restrict__ Bg,
               float* __restrict__ out) {
    const int bid = blockIdx.x;                  // [0,512)
    const int pg  = bid >> 8;
    const int by2 = bid & 255;
    const int b = by2 >> 6, y2 = by2 & 63;
    const int p0 = pg ? 6 : 0, p1 = pg ? 11 : 6;

    const int tid  = threadIdx.x;
    const int lane = tid & 63, w = tid >> 6;
    const int par  = w & 1, slot = w >> 1;
    const int n    = lane & 15, q = lane >> 4;

    __shared__ __align__(16) short Bsh[96 * BP];     // 49920 B
    __shared__ __align__(16) float scr[2][21 * 97];  // 16296 B

    // stage B(b,y2) ONCE
    {
        const short* src = Bg + (size_t)by2 * PLANE;
#pragma unroll
        for (int it = 0; it < 12; ++it) {
            const int j = it * 256 + tid;        // [0,3072)
            *(bf16x8*)&Bsh[(j >> 5) * BP + (j & 31) * 8] = *(const bf16x8*)(src + j * 8);
        }
    }
    __syncthreads();

    const bool v0 = (n >= 10), v3 = (n < 10);
    const int  r0c = v0 ? (n - 10) : 0;
    const int  r3c = v3 ? (n + 38) : 0;
    const short* Bp = &Bsh[par * 48 * BP];

    for (int p = p0; p < p1; ++p) {
        const int dyp = 2 * p + slot;
        const int y   = y2 + 20 - 2 * dyp;
        const bool live = (dyp < 21) && (y >= 0) && (y < 64);

        f32x4 acc[9];
#pragma unroll
        for (int t2 = 0; t2 < 9; ++t2) acc[t2] = (f32x4)0.0f;

        if (live) {
            // A-fragments direct from global (dense 64B-line gather, L3-resident)
            const short* Ap = Ag + ((size_t)(b * 64 + y) * 96 + par * 48) * 256;
            bf16x8 af[3][8];
#pragma unroll
            for (int ks = 0; ks < 8; ++ks)
#pragma unroll
                for (int Xi = 0; Xi < 3; ++Xi)
                    af[Xi][ks] = *(const bf16x8*)(Ap + (Xi * 16 + n) * 256 + ks * 32 + q * 8);

#pragma unroll
            for (int ks = 0; ks < 8; ++ks) {
                const int ko = ks * 32 + q * 8;
                bf16x8 b0 = *(const bf16x8*)&Bp[r0c * BP + ko];     if (!v0) b0 = 0;
                bf16x8 b1 = *(const bf16x8*)&Bp[(n + 6)  * BP + ko];
                bf16x8 b2 = *(const bf16x8*)&Bp[(n + 22) * BP + ko];
                bf16x8 b3 = *(const bf16x8*)&Bp[r3c * BP + ko];     if (!v3) b3 = 0;
                acc[0] = __builtin_amdgcn_mfma_f32_16x16x32_bf16(af[0][ks], b0, acc[0], 0, 0, 0);
                acc[1] = __builtin_amdgcn_mfma_f32_16x16x32_bf16(af[0][ks], b1, acc[1], 0, 0, 0);
                acc[2] = __builtin_amdgcn_mfma_f32_16x16x32_bf16(af[0][ks], b2, acc[2], 0, 0, 0);
                acc[3] = __builtin_amdgcn_mfma_f32_16x16x32_bf16(af[1][ks], b1, acc[3], 0, 0, 0);
                acc[4] = __builtin_amdgcn_mfma_f32_16x16x32_bf16(af[1][ks], b2, acc[4], 0, 0, 0);
                acc[5] = __builtin_amdgcn_mfma_f32_16x16x32_bf16(af[1][ks], b3, acc[5], 0, 0, 0);
                acc[6] = __builtin_amdgcn_mfma_f32_16x16x32_bf16(af[2][ks], b2, acc[6], 0, 0, 0);
                acc[7] = __builtin_amdgcn_mfma_f32_16x16x32_bf16(af[2][ks], b3, acc[7], 0, 0, 0);
                // acc[8] = (X2,U4): all B cols OOB -> stays zero (real zero outputs)
            }

            // scatter C tiles into scratch at (k, x=2*xe+par)
            float* sc = scr[slot];
            const int mb = q * 4;
#pragma unroll
            for (int t2 = 0; t2 < 9; ++t2) {
                const int Xi = (t2 < 3) ? 0 : (t2 < 6 ? 1 : 2);
                constexpr int UJ[9] = {0, 1, 2, 1, 2, 3, 2, 3, 4};
                const int ub = UJ[t2] * 16;
#pragma unroll
                for (int rr = 0; rr < 4; ++rr) {
                    const int xe = Xi * 16 + mb + rr;
                    const int k  = ub + n - xe;
                    if ((unsigned)k < 21u)
                        sc[k * 97 + 2 * xe + par] = acc[t2][rr];
                }
            }
        }
        __syncthreads();

        // cooperative coalesced store of both slots' dyps
#pragma unroll
        for (int it = 0; it < 16; ++it) {
            const int e = it * 256 + tid;        // [0,4096), valid < 4032
            if (e < 4032) {
                const int s  = e / 2016;
                const int f  = e - s * 2016;
                const int k  = f / 96;
                const int x  = f - k * 96;
                const int dd = 2 * p + s;
                const int yd = y2 + 20 - 2 * dd;
                if (dd < 21 && yd >= 0 && yd < 64)
                    out[((size_t)(b * 441 + dd * 21 + k) * 64 + yd) * 96 + x] =
                        scr[s][k * 97 + x] * (1.0f / 256.0f);
            }
        }
        __syncthreads();
    }
}

extern "C" void kernel_launch(void* const* d_in, const int* in_sizes, int n_in,
                              void* d_out, int out_size, void* d_ws, size_t ws_size,
                              hipStream_t stream) {
    const float* in1 = (const float*)d_in[0];
    const float* in2 = (const float*)d_in[1];
    float* out = (float*)d_out;

    short* Ag = (short*)d_ws;                    // 256 planes * 24576 shorts = 12.58 MB
    short* Bg = Ag + (size_t)256 * PLANE;        // 12.58 MB

    corr_prepass<<<dim3(512), dim3(256), 0, stream>>>(in1, in2, Ag, Bg);
    corr_mfma<<<dim3(512), dim3(256), 0, stream>>>(Ag, Bg, out);
}